// Round 3
// baseline (1199.627 us; speedup 1.0000x reference)
//
#include <hip/hip_runtime.h>
#include <math.h>

// Problem constants (from reference)
#define Bq 8
#define Nq 8192
#define Dq 256
#define Qq 4
#define Kq 2048
#define Mq (Nq / Qq)          // 2048 tokens per chunk
#define TT (Bq * Nq)          // 65536 total tokens
#define QUANT_ELEMS ((size_t)TT * Dq)   // 16777216

#define TILE_T 128
#define TILE_C 128
#define DK 32
#define PAD 4

#define FLAG_CAP 16384
#define FLAG_THRESH 3e-5f

// ws layout (bytes)
#define WS_INVE_OFF   0
#define WS_INVX_OFF   32768
#define WS_CNT_OFF    294912
#define WS_LIST_OFF   294928

// ---------------- inverse norms (fast path; feeds main kernel only) --------
__global__ __launch_bounds__(256) void norm_kernel(const float* __restrict__ src,
                                                   float* __restrict__ inv) {
    int row  = blockIdx.x * 4 + (threadIdx.x >> 6);
    int lane = threadIdx.x & 63;
    float4 v = *(const float4*)(src + (size_t)row * Dq + lane * 4);
    float s = v.x * v.x + v.y * v.y + v.z * v.z + v.w * v.w;
    #pragma unroll
    for (int off = 32; off; off >>= 1) s += __shfl_down(s, off, 64);
    if (lane == 0) inv[row] = 1.0f / fmaxf(sqrtf(s), 1e-12f);
}

// ---------------- main: cosine scores + top-2 argmax + gather --------------
__global__ __launch_bounds__(256) void pq_kernel(const float* __restrict__ x,
                                                 const float* __restrict__ embed,
                                                 const float* __restrict__ inv_e,
                                                 const float* __restrict__ inv_x,
                                                 float* __restrict__ out,
                                                 int* __restrict__ flag_cnt,
                                                 int* __restrict__ flag_list) {
    __shared__ __align__(16) float xs[DK][TILE_T + PAD];
    __shared__ __align__(16) float es[DK][TILE_C + PAD];
    __shared__ int ids[TILE_T];

    const int tid = threadIdx.x;
    const int tx  = tid & 15;
    const int ty  = tid >> 4;
    const int t0  = blockIdx.x * TILE_T;
    const int q   = (t0 % Nq) / Mq;
    const float* eq   = embed + (size_t)q * Kq * Dq;
    const float* invq = inv_e + q * Kq;

    float best1[8], best2[8];
    int   bidx[8];
    #pragma unroll
    for (int i = 0; i < 8; ++i) { best1[i] = -2.0f; best2[i] = -2.0f; bidx[i] = 0; }

    for (int c0 = 0; c0 < Kq; c0 += TILE_C) {
        float acc[8][8];
        #pragma unroll
        for (int i = 0; i < 8; ++i)
            #pragma unroll
            for (int j = 0; j < 8; ++j) acc[i][j] = 0.0f;

        for (int d0 = 0; d0 < Dq; d0 += DK) {
            __syncthreads();
            #pragma unroll
            for (int kk = 0; kk < 4; ++kk) {
                int f   = kk * 256 + tid;
                int tok = f >> 3;
                int dq  = f & 7;
                float sx = inv_x[t0 + tok];
                float4 v = *(const float4*)(x + (size_t)(t0 + tok) * Dq + d0 + dq * 4);
                xs[dq * 4 + 0][tok] = v.x * sx;
                xs[dq * 4 + 1][tok] = v.y * sx;
                xs[dq * 4 + 2][tok] = v.z * sx;
                xs[dq * 4 + 3][tok] = v.w * sx;
                float se = invq[c0 + tok];
                float4 w = *(const float4*)(eq + (size_t)(c0 + tok) * Dq + d0 + dq * 4);
                es[dq * 4 + 0][tok] = w.x * se;
                es[dq * 4 + 1][tok] = w.y * se;
                es[dq * 4 + 2][tok] = w.z * se;
                es[dq * 4 + 3][tok] = w.w * se;
            }
            __syncthreads();

            #pragma unroll
            for (int d = 0; d < DK; ++d) {
                float4 xa = *(const float4*)&xs[d][ty * 4];
                float4 xb = *(const float4*)&xs[d][64 + ty * 4];
                float4 ea = *(const float4*)&es[d][tx * 4];
                float4 eb = *(const float4*)&es[d][64 + tx * 4];
                float xr[8] = {xa.x, xa.y, xa.z, xa.w, xb.x, xb.y, xb.z, xb.w};
                float ec[8] = {ea.x, ea.y, ea.z, ea.w, eb.x, eb.y, eb.z, eb.w};
                #pragma unroll
                for (int i = 0; i < 8; ++i)
                    #pragma unroll
                    for (int j = 0; j < 8; ++j)
                        acc[i][j] = fmaf(xr[i], ec[j], acc[i][j]);
            }
        }

        #pragma unroll
        for (int i = 0; i < 8; ++i) {
            #pragma unroll
            for (int j = 0; j < 8; ++j) {
                float s = acc[i][j];
                int   c = (j < 4) ? (c0 + tx * 4 + j) : (c0 + 64 + tx * 4 + (j - 4));
                if (s > best1[i]) { best2[i] = best1[i]; best1[i] = s; bidx[i] = c; }
                else if (s > best2[i]) { best2[i] = s; }
            }
        }
    }

    #pragma unroll
    for (int i = 0; i < 8; ++i) {
        float b1 = best1[i], b2 = best2[i]; int bc = bidx[i];
        #pragma unroll
        for (int m = 1; m < 16; m <<= 1) {
            float o1 = __shfl_xor(b1, m, 64);
            float o2 = __shfl_xor(b2, m, 64);
            int   oc = __shfl_xor(bc, m, 64);
            float lo = fminf(b1, o1);
            b2 = fmaxf(fmaxf(b2, o2), lo);
            if (o1 > b1 || (o1 == b1 && oc < bc)) { b1 = o1; bc = oc; }
        }
        int r = (i < 4) ? (ty * 4 + i) : (64 + ty * 4 + (i - 4));
        if (tx == 0) {
            ids[r] = bc;
            out[QUANT_ELEMS + (size_t)(t0 + r)] = (float)bc;
            if (b1 - b2 < FLAG_THRESH) {
                int pos = atomicAdd(flag_cnt, 1);
                if (pos < FLAG_CAP) flag_list[pos] = t0 + r;
            }
        }
    }
    __syncthreads();

    #pragma unroll 4
    for (int kk = 0; kk < 32; ++kk) {
        int f   = kk * 256 + tid;
        int r   = f >> 6;
        int col = f & 63;
        int code = ids[r];
        float4 v = *(const float4*)(eq + (size_t)code * Dq + col * 4);
        *(float4*)(out + (size_t)(t0 + r) * Dq + col * 4) = v;
    }

    if (blockIdx.x == 0 && tid == 0) out[QUANT_ELEMS + TT] = 0.0f;
}

// ---------------- numpy-fp32 emulation helpers -----------------------------
// numpy pairwise sum of squares over a 128-block: 8 scalar accumulators,
// tree combine ((r0+r1)+(r2+r3))+((r4+r5)+(r6+r7)). Squares rounded first.
__device__ __forceinline__ float np_pw128_sq(const float* a) {
#pragma clang fp contract(off)
    float r[8];
    #pragma unroll
    for (int j = 0; j < 8; ++j) { float v = a[j]; r[j] = v * v; }
    for (int i = 8; i < 128; i += 8) {
        #pragma unroll
        for (int j = 0; j < 8; ++j) { float v = a[i + j]; r[j] = r[j] + v * v; }
    }
    return ((r[0] + r[1]) + (r[2] + r[3])) + ((r[4] + r[5]) + (r[6] + r[7]));
}

// IEEE-correct fp32 ops via double (double-rounding safe for p=24)
__device__ __forceinline__ float f32_div(float a, float b) {
    return (float)((double)a / (double)b);
}
__device__ __forceinline__ float np_norm256(const float* a) {
#pragma clang fp contract(off)
    float n2 = np_pw128_sq(a) + np_pw128_sq(a + 128);
    float nm = (float)sqrt((double)n2);
    return fmaxf(nm, 1e-12f);
}

// ---------------- fixup: numpy-fp32-emulating re-rank of flagged tokens ----
__global__ __launch_bounds__(256) void fixup_np(const float* __restrict__ x,
                                                const float* __restrict__ embed,
                                                float* __restrict__ out,
                                                const int* __restrict__ flag_cnt,
                                                const int* __restrict__ flag_list) {
#pragma clang fp contract(off)
    __shared__ float xn[Dq];
    __shared__ float ssc[256];
    __shared__ int   sid[256];
    __shared__ float s_nm;
    int count = *flag_cnt;
    if (count > FLAG_CAP) count = FLAG_CAP;
    const int tid = threadIdx.x;

    for (int i = blockIdx.x; i < count; i += gridDim.x) {
        int t = flag_list[i];
        int q = (t % Nq) / Mq;
        const float* xr  = x + (size_t)t * Dq;
        const float* eqb = embed + (size_t)q * Kq * Dq;

        if (tid == 0) s_nm = np_norm256(xr);
        __syncthreads();
        xn[tid] = f32_div(xr[tid], s_nm);       // per-element fp32 divide (numpy l2norm)
        __syncthreads();

        float bs = -2.0f; int bk = 0;
        #pragma unroll 1
        for (int j = 0; j < 8; ++j) {
            int k = tid * 8 + j;                // ascending codes within thread
            const float* er = eqb + (size_t)k * Dq;
            float nme = np_norm256(er);
            // np.einsum fp32 SSE emulation: 4 lane accumulators, lane j sums
            // d == j (mod 4) ascending, mul/add separately rounded, tree (l0+l1)+(l2+l3)
            float l0 = 0.0f, l1 = 0.0f, l2 = 0.0f, l3 = 0.0f;
            for (int d = 0; d < Dq; d += 4) {
                float e0 = f32_div(er[d + 0], nme);
                float e1 = f32_div(er[d + 1], nme);
                float e2 = f32_div(er[d + 2], nme);
                float e3 = f32_div(er[d + 3], nme);
                l0 = l0 + xn[d + 0] * e0;
                l1 = l1 + xn[d + 1] * e1;
                l2 = l2 + xn[d + 2] * e2;
                l3 = l3 + xn[d + 3] * e3;
            }
            float sc = (l0 + l1) + (l2 + l3);
            if (sc > bs) { bs = sc; bk = k; }   // strict > : first-max wins
        }
        ssc[tid] = bs; sid[tid] = bk;
        __syncthreads();
        for (int off = 128; off; off >>= 1) {
            if (tid < off) {
                float os = ssc[tid + off]; int oi = sid[tid + off];
                if (os > ssc[tid] || (os == ssc[tid] && oi < sid[tid])) {
                    ssc[tid] = os; sid[tid] = oi;
                }
            }
            __syncthreads();
        }
        int kbest = sid[0];
        if (tid == 0) out[QUANT_ELEMS + (size_t)t] = (float)kbest;
        if (tid < 64) {
            float4 v = *(const float4*)(eqb + (size_t)kbest * Dq + tid * 4);
            *(float4*)(out + (size_t)t * Dq + tid * 4) = v;
        }
        __syncthreads();
    }
}

extern "C" void kernel_launch(void* const* d_in, const int* in_sizes, int n_in,
                              void* d_out, int out_size, void* d_ws, size_t ws_size,
                              hipStream_t stream) {
    const float* x     = (const float*)d_in[0];
    const float* embed = (const float*)d_in[1];
    float* out = (float*)d_out;
    char* ws = (char*)d_ws;
    float* inv_e = (float*)(ws + WS_INVE_OFF);
    float* inv_x = (float*)(ws + WS_INVX_OFF);
    int* flag_cnt  = (int*)(ws + WS_CNT_OFF);
    int* flag_list = (int*)(ws + WS_LIST_OFF);

    hipMemsetAsync(flag_cnt, 0, sizeof(int), stream);
    norm_kernel<<<(Qq * Kq) / 4, 256, 0, stream>>>(embed, inv_e);
    norm_kernel<<<TT / 4, 256, 0, stream>>>(x, inv_x);
    pq_kernel<<<TT / TILE_T, 256, 0, stream>>>(x, embed, inv_e, inv_x, out,
                                               flag_cnt, flag_list);
    fixup_np<<<256, 256, 0, stream>>>(x, embed, out, flag_cnt, flag_list);
}